// Round 2
// baseline (103.877 us; speedup 1.0000x reference)
//
#include <hip/hip_runtime.h>
#include <math.h>

// ---------------------------------------------------------------------------
// MyGaussianModel: bind 2M gaussians to 9976 triangle faces.
// Phase 1: per-face frame/quat/scale precompute into d_ws (798 KB, L2-resident).
// Phase 2: per-gaussian transform + activation. 4 gaussians/thread so ALL
//          global traffic is aligned dwordx4 (16 B/lane).
// ---------------------------------------------------------------------------

struct F3 { float x, y, z; };
__device__ __forceinline__ F3 mkf3(float x, float y, float z) { F3 r; r.x = x; r.y = y; r.z = z; return r; }
__device__ __forceinline__ F3 f3sub(F3 a, F3 b) { return mkf3(a.x - b.x, a.y - b.y, a.z - b.z); }
__device__ __forceinline__ F3 f3add(F3 a, F3 b) { return mkf3(a.x + b.x, a.y + b.y, a.z + b.z); }
__device__ __forceinline__ F3 f3scl(F3 a, float s) { return mkf3(a.x * s, a.y * s, a.z * s); }
__device__ __forceinline__ float f3dot(F3 a, F3 b) { return a.x * b.x + a.y * b.y + a.z * b.z; }
__device__ __forceinline__ F3 f3cross(F3 a, F3 b) {
    return mkf3(a.y * b.z - a.z * b.y, a.z * b.x - a.x * b.z, a.x * b.y - a.y * b.x);
}

__device__ void face_geom(const float* __restrict__ verts, const int* __restrict__ faces, int f,
                          F3& a0, F3& a1, F3& a2, F3& ctr, float& fs, float4& quat_wxyz)
{
    int i0 = faces[3 * f + 0], i1 = faces[3 * f + 1], i2 = faces[3 * f + 2];
    F3 v0 = mkf3(verts[3 * i0], verts[3 * i0 + 1], verts[3 * i0 + 2]);
    F3 v1 = mkf3(verts[3 * i1], verts[3 * i1 + 1], verts[3 * i1 + 2]);
    F3 v2 = mkf3(verts[3 * i2], verts[3 * i2 + 1], verts[3 * i2 + 2]);

    ctr = f3scl(f3add(f3add(v0, v1), v2), (1.0f / 3.0f));

    F3 e1 = f3sub(v1, v0);
    float d1 = f3dot(e1, e1);
    float s0 = sqrtf(d1);
    a0 = f3scl(e1, 1.0f / sqrtf(fmaxf(d1, 1e-20f)));

    F3 e2 = f3sub(v2, v0);
    F3 c = f3cross(a0, e2);
    float dc = f3dot(c, c);
    a1 = f3scl(c, 1.0f / sqrtf(fmaxf(dc, 1e-20f)));

    F3 c2 = f3cross(a1, a0);
    float dc2 = f3dot(c2, c2);
    F3 n2 = f3scl(c2, 1.0f / sqrtf(fmaxf(dc2, 1e-20f)));
    a2 = mkf3(-n2.x, -n2.y, -n2.z);

    float s1 = fabsf(f3dot(c, a1));
    fs = 0.5f * (s0 + s1);

    float r00 = a0.x, r10 = a0.y, r20 = a0.z;
    float r01 = a1.x, r11 = a1.y, r21 = a1.z;
    float r02 = a2.x, r12 = a2.y, r22 = a2.z;
    float t = r00 + r11 + r22;

    float cand[4][4] = {
        { 1.0f + r00 - r11 - r22, r10 + r01,              r20 + r02,              r21 - r12 },
        { r10 + r01,              1.0f - r00 + r11 - r22, r21 + r12,              r02 - r20 },
        { r20 + r02,              r21 + r12,              1.0f - r00 - r11 + r22, r10 - r01 },
        { r21 - r12,              r02 - r20,              r10 - r01,              1.0f + t  }
    };
    float dec[4] = { r00, r11, r22, t };
    int ch = 0;
    float best = dec[0];
#pragma unroll
    for (int j = 1; j < 4; ++j) {
        if (dec[j] > best) { best = dec[j]; ch = j; }
    }
    float qx = cand[ch][0], qy = cand[ch][1], qz = cand[ch][2], qw = cand[ch][3];
    float inv = 1.0f / sqrtf(qx * qx + qy * qy + qz * qz + qw * qw);
    quat_wxyz = make_float4(qw * inv, qx * inv, qy * inv, qz * inv);
}

__global__ __launch_bounds__(256)
void face_kernel(const float* __restrict__ verts, const int* __restrict__ faces,
                 float4* __restrict__ fd, int nf)
{
    int f = blockIdx.x * 256 + threadIdx.x;
    if (f >= nf) return;
    F3 a0, a1, a2, ctr; float fs; float4 quat;
    face_geom(verts, faces, f, a0, a1, a2, ctr, fs, quat);
    fd[5 * f + 0] = make_float4(a0.x, a0.y, a0.z, ctr.x);
    fd[5 * f + 1] = make_float4(a1.x, a1.y, a1.z, ctr.y);
    fd[5 * f + 2] = make_float4(a2.x, a2.y, a2.z, ctr.z);
    fd[5 * f + 3] = quat;
    fd[5 * f + 4] = make_float4(fs, 0.0f, 0.0f, 0.0f);
}

// Core per-gaussian math. All inputs in registers; writes 14 floats to po[].
__device__ __forceinline__ void gauss_compute(
    float4 f0, float4 f1, float4 f2, float4 fq, float fs,
    float x, float y, float z,
    float op, float sc0, float sc1, float sc2,
    float4 r, float d0, float d1, float d2,
    float* __restrict__ po)
{
    float gx = (f0.x * x + f1.x * y + f2.x * z) * fs + f0.w;
    float gy = (f0.y * x + f1.y * y + f2.y * z) * fs + f1.w;
    float gz = (f0.z * x + f1.z * y + f2.z * z) * fs + f2.w;

    float s0 = expf(sc0) * fs;
    float s1 = expf(sc1) * fs;
    float s2 = expf(sc2) * fs;

    float o = 1.0f / (1.0f + expf(-op));

    float rn = sqrtf(r.x * r.x + r.y * r.y + r.z * r.z + r.w * r.w) + 1e-12f;
    float rinv = 1.0f / rn;
    float rw = r.x * rinv, rx = r.y * rinv, ry = r.z * rinv, rz = r.w * rinv;

    float pw = fq.x, px = fq.y, py = fq.z, pz = fq.w;
    float vx = pw * rx + rw * px + (py * rz - pz * ry);
    float vy = pw * ry + rw * py + (pz * rx - px * rz);
    float vz = pw * rz + rw * pz + (px * ry - py * rx);
    float vw = pw * rw - (px * rx + py * ry + pz * rz);
    float qinv = 1.0f / sqrtf(vx * vx + vy * vy + vz * vz + vw * vw);

    float c0 = fminf(fmaxf((0.5f + 0.282f * d0) * 255.0f, 0.0f), 255.0f);
    float c1 = fminf(fmaxf((0.5f + 0.282f * d1) * 255.0f, 0.0f), 255.0f);
    float c2 = fminf(fmaxf((0.5f + 0.282f * d2) * 255.0f, 0.0f), 255.0f);
    float c3 = fminf(fmaxf(o * 255.0f, 0.0f), 255.0f);

    po[0]  = gx;        po[1]  = gy;        po[2]  = gz;
    po[3]  = s0;        po[4]  = s1;        po[5]  = s2;
    po[6]  = c0;        po[7]  = c1;        po[8]  = c2;        po[9] = c3;
    po[10] = vw * qinv; po[11] = vx * qinv; po[12] = vy * qinv; po[13] = vz * qinv;
}

// 4 gaussians per thread: every global access is an aligned dwordx4.
__global__ __launch_bounds__(256)
void gauss_main4(const float* __restrict__ xyz, const float* __restrict__ opa,
                 const float* __restrict__ scl, const float4* __restrict__ rot_raw,
                 const float* __restrict__ fdc, const int* __restrict__ binding,
                 const float4* __restrict__ face, float* __restrict__ out, int n)
{
    int t = blockIdx.x * 256 + threadIdx.x;
    int i0 = t * 4;
    if (i0 >= n) return;

    if (i0 + 3 < n) {
        const float4* xyz4 = (const float4*)xyz;
        const float4* scl4 = (const float4*)scl;
        const float4* fdc4 = (const float4*)fdc;

        float xs[12], ss[12], ff[12], os[4];
        *(float4*)&xs[0] = xyz4[3 * t];     *(float4*)&xs[4] = xyz4[3 * t + 1]; *(float4*)&xs[8] = xyz4[3 * t + 2];
        *(float4*)&ss[0] = scl4[3 * t];     *(float4*)&ss[4] = scl4[3 * t + 1]; *(float4*)&ss[8] = scl4[3 * t + 2];
        *(float4*)&ff[0] = fdc4[3 * t];     *(float4*)&ff[4] = fdc4[3 * t + 1]; *(float4*)&ff[8] = fdc4[3 * t + 2];
        *(float4*)&os[0] = ((const float4*)opa)[t];
        int4 bb = ((const int4*)binding)[t];
        int bs[4] = { bb.x, bb.y, bb.z, bb.w };
        float4 rr[4] = { rot_raw[i0], rot_raw[i0 + 1], rot_raw[i0 + 2], rot_raw[i0 + 3] };

        float outv[56];
#pragma unroll
        for (int j = 0; j < 4; ++j) {
            int b = bs[j];
            float4 f0 = face[5 * b + 0];
            float4 f1 = face[5 * b + 1];
            float4 f2 = face[5 * b + 2];
            float4 fq = face[5 * b + 3];
            float fsc = face[5 * b + 4].x;
            gauss_compute(f0, f1, f2, fq, fsc,
                          xs[3 * j], xs[3 * j + 1], xs[3 * j + 2],
                          os[j], ss[3 * j], ss[3 * j + 1], ss[3 * j + 2],
                          rr[j], ff[3 * j], ff[3 * j + 1], ff[3 * j + 2],
                          &outv[14 * j]);
        }

        float4* o4 = (float4*)out + 14 * (size_t)t;
#pragma unroll
        for (int k = 0; k < 14; ++k) o4[k] = *(const float4*)&outv[4 * k];
    } else {
        // scalar tail (n % 4 != 0)
        for (int i = i0; i < n; ++i) {
            int b = binding[i];
            float4 f0 = face[5 * b + 0];
            float4 f1 = face[5 * b + 1];
            float4 f2 = face[5 * b + 2];
            float4 fq = face[5 * b + 3];
            float fsc = face[5 * b + 4].x;
            float tmp[14];
            gauss_compute(f0, f1, f2, fq, fsc,
                          xyz[3 * i], xyz[3 * i + 1], xyz[3 * i + 2],
                          opa[i], scl[3 * i], scl[3 * i + 1], scl[3 * i + 2],
                          rot_raw[i], fdc[3 * i], fdc[3 * i + 1], fdc[3 * i + 2],
                          tmp);
            float* po = out + (size_t)i * 14;
#pragma unroll
            for (int k = 0; k < 14; ++k) po[k] = tmp[k];
        }
    }
}

// Fallback if ws_size is too small for the face table (not expected).
__global__ __launch_bounds__(256)
void gauss_fused(const float* __restrict__ verts, const int* __restrict__ faces,
                 const float* __restrict__ xyz, const float* __restrict__ opa,
                 const float* __restrict__ scl, const float4* __restrict__ rot_raw,
                 const float* __restrict__ fdc, const int* __restrict__ binding,
                 float* __restrict__ out, int n)
{
    int i = blockIdx.x * 256 + threadIdx.x;
    if (i >= n) return;
    int b = binding[i];
    F3 a0, a1, a2, ctr; float fs; float4 quat;
    face_geom(verts, faces, b, a0, a1, a2, ctr, fs, quat);
    float4 f0 = make_float4(a0.x, a0.y, a0.z, ctr.x);
    float4 f1 = make_float4(a1.x, a1.y, a1.z, ctr.y);
    float4 f2 = make_float4(a2.x, a2.y, a2.z, ctr.z);
    float tmp[14];
    gauss_compute(f0, f1, f2, quat, fs,
                  xyz[3 * i], xyz[3 * i + 1], xyz[3 * i + 2],
                  opa[i], scl[3 * i], scl[3 * i + 1], scl[3 * i + 2],
                  rot_raw[i], fdc[3 * i], fdc[3 * i + 1], fdc[3 * i + 2],
                  tmp);
    float* po = out + (size_t)i * 14;
#pragma unroll
    for (int k = 0; k < 14; ++k) po[k] = tmp[k];
}

extern "C" void kernel_launch(void* const* d_in, const int* in_sizes, int n_in,
                              void* d_out, int out_size, void* d_ws, size_t ws_size,
                              hipStream_t stream)
{
    const float* verts   = (const float*)d_in[0];
    const float* xyz     = (const float*)d_in[1];
    const float* opa     = (const float*)d_in[2];
    const float* scl     = (const float*)d_in[3];
    const float* rot     = (const float*)d_in[4];
    const float* fdc     = (const float*)d_in[5];
    // d_in[6] = features_rest : unused by the reference output — never read.
    const int*   faces   = (const int*)d_in[7];
    const int*   binding = (const int*)d_in[8];

    int n      = in_sizes[8];        // N_GAUSS
    int nfaces = in_sizes[7] / 3;    // N_FACES
    float* out = (float*)d_out;

    size_t need = (size_t)nfaces * 5 * sizeof(float4);

    if (ws_size >= need) {
        float4* face = (float4*)d_ws;
        hipLaunchKernelGGL(face_kernel, dim3((nfaces + 255) / 256), dim3(256), 0, stream,
                           verts, faces, face, nfaces);
        int nthreads = (n + 3) / 4;
        hipLaunchKernelGGL(gauss_main4, dim3((nthreads + 255) / 256), dim3(256), 0, stream,
                           xyz, opa, scl, (const float4*)rot, fdc, binding, face, out, n);
    } else {
        hipLaunchKernelGGL(gauss_fused, dim3((n + 255) / 256), dim3(256), 0, stream,
                           verts, faces, xyz, opa, scl, (const float4*)rot, fdc, binding, out, n);
    }
}

// Round 3
// 47.594 us; speedup vs baseline: 2.1826x; 2.1826x over previous
//
#include <hip/hip_runtime.h>
#include <math.h>

// ---------------------------------------------------------------------------
// MyGaussianModel: bind 2M gaussians to 9976 triangle faces.
// Phase 1: per-face frame/quat/scale precompute into d_ws (798 KB, L2-resident).
// Phase 2: per-gaussian transform + activation, with LDS-staged I/O so every
//          global load/store is a fully-coalesced dwordx4 (lane i -> base+16i).
// ---------------------------------------------------------------------------

struct F3 { float x, y, z; };
__device__ __forceinline__ F3 mkf3(float x, float y, float z) { F3 r; r.x = x; r.y = y; r.z = z; return r; }
__device__ __forceinline__ F3 f3sub(F3 a, F3 b) { return mkf3(a.x - b.x, a.y - b.y, a.z - b.z); }
__device__ __forceinline__ F3 f3add(F3 a, F3 b) { return mkf3(a.x + b.x, a.y + b.y, a.z + b.z); }
__device__ __forceinline__ F3 f3scl(F3 a, float s) { return mkf3(a.x * s, a.y * s, a.z * s); }
__device__ __forceinline__ float f3dot(F3 a, F3 b) { return a.x * b.x + a.y * b.y + a.z * b.z; }
__device__ __forceinline__ F3 f3cross(F3 a, F3 b) {
    return mkf3(a.y * b.z - a.z * b.y, a.z * b.x - a.x * b.z, a.x * b.y - a.y * b.x);
}

__device__ void face_geom(const float* __restrict__ verts, const int* __restrict__ faces, int f,
                          F3& a0, F3& a1, F3& a2, F3& ctr, float& fs, float4& quat_wxyz)
{
    int i0 = faces[3 * f + 0], i1 = faces[3 * f + 1], i2 = faces[3 * f + 2];
    F3 v0 = mkf3(verts[3 * i0], verts[3 * i0 + 1], verts[3 * i0 + 2]);
    F3 v1 = mkf3(verts[3 * i1], verts[3 * i1 + 1], verts[3 * i1 + 2]);
    F3 v2 = mkf3(verts[3 * i2], verts[3 * i2 + 1], verts[3 * i2 + 2]);

    ctr = f3scl(f3add(f3add(v0, v1), v2), (1.0f / 3.0f));

    F3 e1 = f3sub(v1, v0);
    float d1 = f3dot(e1, e1);
    float s0 = sqrtf(d1);
    a0 = f3scl(e1, 1.0f / sqrtf(fmaxf(d1, 1e-20f)));

    F3 e2 = f3sub(v2, v0);
    F3 c = f3cross(a0, e2);
    float dc = f3dot(c, c);
    a1 = f3scl(c, 1.0f / sqrtf(fmaxf(dc, 1e-20f)));

    F3 c2 = f3cross(a1, a0);
    float dc2 = f3dot(c2, c2);
    F3 n2 = f3scl(c2, 1.0f / sqrtf(fmaxf(dc2, 1e-20f)));
    a2 = mkf3(-n2.x, -n2.y, -n2.z);

    float s1 = fabsf(f3dot(c, a1));
    fs = 0.5f * (s0 + s1);

    float r00 = a0.x, r10 = a0.y, r20 = a0.z;
    float r01 = a1.x, r11 = a1.y, r21 = a1.z;
    float r02 = a2.x, r12 = a2.y, r22 = a2.z;
    float t = r00 + r11 + r22;

    float cand[4][4] = {
        { 1.0f + r00 - r11 - r22, r10 + r01,              r20 + r02,              r21 - r12 },
        { r10 + r01,              1.0f - r00 + r11 - r22, r21 + r12,              r02 - r20 },
        { r20 + r02,              r21 + r12,              1.0f - r00 - r11 + r22, r10 - r01 },
        { r21 - r12,              r02 - r20,              r10 - r01,              1.0f + t  }
    };
    float dec[4] = { r00, r11, r22, t };
    int ch = 0;
    float best = dec[0];
#pragma unroll
    for (int j = 1; j < 4; ++j) {
        if (dec[j] > best) { best = dec[j]; ch = j; }
    }
    float qx = cand[ch][0], qy = cand[ch][1], qz = cand[ch][2], qw = cand[ch][3];
    float inv = 1.0f / sqrtf(qx * qx + qy * qy + qz * qz + qw * qw);
    quat_wxyz = make_float4(qw * inv, qx * inv, qy * inv, qz * inv);
}

__global__ __launch_bounds__(256)
void face_kernel(const float* __restrict__ verts, const int* __restrict__ faces,
                 float4* __restrict__ fd, int nf)
{
    int f = blockIdx.x * 256 + threadIdx.x;
    if (f >= nf) return;
    F3 a0, a1, a2, ctr; float fs; float4 quat;
    face_geom(verts, faces, f, a0, a1, a2, ctr, fs, quat);
    fd[5 * f + 0] = make_float4(a0.x, a0.y, a0.z, ctr.x);
    fd[5 * f + 1] = make_float4(a1.x, a1.y, a1.z, ctr.y);
    fd[5 * f + 2] = make_float4(a2.x, a2.y, a2.z, ctr.z);
    fd[5 * f + 3] = quat;
    fd[5 * f + 4] = make_float4(fs, 0.0f, 0.0f, 0.0f);
}

// ---------------------------------------------------------------------------
// Main per-gaussian kernel: 256 gaussians per block, LDS-staged input+output.
// ---------------------------------------------------------------------------
__global__ __launch_bounds__(256)
void gauss_lds(const float* __restrict__ xyz, const float* __restrict__ opa,
               const float* __restrict__ scl, const float4* __restrict__ rot_raw,
               const float* __restrict__ fdc, const int* __restrict__ binding,
               const float4* __restrict__ face, float* __restrict__ out, int n)
{
    __shared__ float s_xyz[768];
    __shared__ float s_scl[768];
    __shared__ float s_fdc[768];
    __shared__ float s_out[256 * 15];   // stride 15: gcd(15,32)=1 -> conflict-free

    int tid = threadIdx.x;
    int g0  = blockIdx.x * 256;         // first gaussian of this block
    int cnt = n - g0; if (cnt > 256) cnt = 256;

    // ---- stage stride-12 inputs via fully-coalesced float4 loads ----
    int nfl = cnt * 3;                  // floats per array for this block
    int nf4 = nfl >> 2;
    const float4* x4 = (const float4*)(xyz + (size_t)g0 * 3);   // g0*12 B, 16B-aligned (g0 % 256 == 0)
    const float4* s4 = (const float4*)(scl + (size_t)g0 * 3);
    const float4* f4 = (const float4*)(fdc + (size_t)g0 * 3);
    if (tid < nf4) {
        *(float4*)&s_xyz[4 * tid] = x4[tid];
        *(float4*)&s_scl[4 * tid] = s4[tid];
        *(float4*)&s_fdc[4 * tid] = f4[tid];
    }
    // scalar tail (only if cnt*3 % 4 != 0 — not the case for cnt in {256,128})
    for (int j = (nf4 << 2) + tid; j < nfl; j += 256) {
        s_xyz[j] = xyz[(size_t)g0 * 3 + j];
        s_scl[j] = scl[(size_t)g0 * 3 + j];
        s_fdc[j] = fdc[(size_t)g0 * 3 + j];
    }
    __syncthreads();

    // ---- per-gaussian compute ----
    if (tid < cnt) {
        int i = g0 + tid;
        int b = binding[i];                       // coalesced dword
        float4 f0 = face[5 * b + 0];
        float4 f1 = face[5 * b + 1];
        float4 f2 = face[5 * b + 2];
        float4 fq = face[5 * b + 3];
        float fs  = face[5 * b + 4].x;

        float x = s_xyz[3 * tid + 0], y = s_xyz[3 * tid + 1], z = s_xyz[3 * tid + 2];
        float gx = (f0.x * x + f1.x * y + f2.x * z) * fs + f0.w;
        float gy = (f0.y * x + f1.y * y + f2.y * z) * fs + f1.w;
        float gz = (f0.z * x + f1.z * y + f2.z * z) * fs + f2.w;

        float s0 = expf(s_scl[3 * tid + 0]) * fs;
        float s1 = expf(s_scl[3 * tid + 1]) * fs;
        float s2 = expf(s_scl[3 * tid + 2]) * fs;

        float o = 1.0f / (1.0f + expf(-opa[i]));  // coalesced dword

        float4 r = rot_raw[i];                    // coalesced dwordx4
        float rinv = 1.0f / (sqrtf(r.x * r.x + r.y * r.y + r.z * r.z + r.w * r.w) + 1e-12f);
        float rw = r.x * rinv, rx = r.y * rinv, ry = r.z * rinv, rz = r.w * rinv;

        // fq (wxyz) is unit; reference's /(norm+1e-12) rounds to /1.0 in f32.
        float pw = fq.x, px = fq.y, py = fq.z, pz = fq.w;
        float vx = pw * rx + rw * px + (py * rz - pz * ry);
        float vy = pw * ry + rw * py + (pz * rx - px * rz);
        float vz = pw * rz + rw * pz + (px * ry - py * rx);
        float vw = pw * rw - (px * rx + py * ry + pz * rz);
        float qinv = 1.0f / sqrtf(vx * vx + vy * vy + vz * vz + vw * vw);

        float c0 = fminf(fmaxf((0.5f + 0.282f * s_fdc[3 * tid + 0]) * 255.0f, 0.0f), 255.0f);
        float c1 = fminf(fmaxf((0.5f + 0.282f * s_fdc[3 * tid + 1]) * 255.0f, 0.0f), 255.0f);
        float c2 = fminf(fmaxf((0.5f + 0.282f * s_fdc[3 * tid + 2]) * 255.0f, 0.0f), 255.0f);
        float c3 = fminf(fmaxf(o * 255.0f, 0.0f), 255.0f);

        float* po = &s_out[tid * 15];             // stride-15 write: conflict-free
        po[0]  = gx;        po[1]  = gy;        po[2]  = gz;
        po[3]  = s0;        po[4]  = s1;        po[5]  = s2;
        po[6]  = c0;        po[7]  = c1;        po[8]  = c2;        po[9] = c3;
        po[10] = vw * qinv; po[11] = vx * qinv; po[12] = vy * qinv; po[13] = vz * qinv;
    }
    __syncthreads();

    // ---- fully-coalesced float4 copy-out ----
    int nflo = cnt * 14;
    int nfo4 = nflo >> 2;                         // 896 for full block
    float4* o4 = (float4*)(out + (size_t)g0 * 14);// g0*56 B, 16B-aligned
    for (int j = tid; j < nfo4; j += 256) {
        int fbase = 4 * j;
        float a = s_out[((fbase + 0) / 14) * 15 + (fbase + 0) % 14];
        float bb = s_out[((fbase + 1) / 14) * 15 + (fbase + 1) % 14];
        float cc = s_out[((fbase + 2) / 14) * 15 + (fbase + 2) % 14];
        float dd = s_out[((fbase + 3) / 14) * 15 + (fbase + 3) % 14];
        o4[j] = make_float4(a, bb, cc, dd);
    }
    for (int f = (nfo4 << 2) + tid; f < nflo; f += 256) {
        out[(size_t)g0 * 14 + f] = s_out[(f / 14) * 15 + f % 14];
    }
}

// Fallback if ws_size is too small for the face table (not expected).
__global__ __launch_bounds__(256)
void gauss_fused(const float* __restrict__ verts, const int* __restrict__ faces,
                 const float* __restrict__ xyz, const float* __restrict__ opa,
                 const float* __restrict__ scl, const float4* __restrict__ rot_raw,
                 const float* __restrict__ fdc, const int* __restrict__ binding,
                 float* __restrict__ out, int n)
{
    int i = blockIdx.x * 256 + threadIdx.x;
    if (i >= n) return;
    int b = binding[i];
    F3 a0, a1, a2, ctr; float fs; float4 quat;
    face_geom(verts, faces, b, a0, a1, a2, ctr, fs, quat);
    float4 f0 = make_float4(a0.x, a0.y, a0.z, ctr.x);
    float4 f1 = make_float4(a1.x, a1.y, a1.z, ctr.y);
    float4 f2 = make_float4(a2.x, a2.y, a2.z, ctr.z);

    float x = xyz[3 * i], y = xyz[3 * i + 1], z = xyz[3 * i + 2];
    float gx = (f0.x * x + f1.x * y + f2.x * z) * fs + f0.w;
    float gy = (f0.y * x + f1.y * y + f2.y * z) * fs + f1.w;
    float gz = (f0.z * x + f1.z * y + f2.z * z) * fs + f2.w;
    float s0 = expf(scl[3 * i + 0]) * fs;
    float s1 = expf(scl[3 * i + 1]) * fs;
    float s2 = expf(scl[3 * i + 2]) * fs;
    float o = 1.0f / (1.0f + expf(-opa[i]));
    float4 r = rot_raw[i];
    float rinv = 1.0f / (sqrtf(r.x * r.x + r.y * r.y + r.z * r.z + r.w * r.w) + 1e-12f);
    float rw = r.x * rinv, rx = r.y * rinv, ry = r.z * rinv, rz = r.w * rinv;
    float pw = quat.x, px = quat.y, py = quat.z, pz = quat.w;
    float vx = pw * rx + rw * px + (py * rz - pz * ry);
    float vy = pw * ry + rw * py + (pz * rx - px * rz);
    float vz = pw * rz + rw * pz + (px * ry - py * rx);
    float vw = pw * rw - (px * rx + py * ry + pz * rz);
    float qinv = 1.0f / sqrtf(vx * vx + vy * vy + vz * vz + vw * vw);
    float* po = out + (size_t)i * 14;
    po[0] = gx; po[1] = gy; po[2] = gz;
    po[3] = s0; po[4] = s1; po[5] = s2;
    po[6] = fminf(fmaxf((0.5f + 0.282f * fdc[3 * i + 0]) * 255.0f, 0.0f), 255.0f);
    po[7] = fminf(fmaxf((0.5f + 0.282f * fdc[3 * i + 1]) * 255.0f, 0.0f), 255.0f);
    po[8] = fminf(fmaxf((0.5f + 0.282f * fdc[3 * i + 2]) * 255.0f, 0.0f), 255.0f);
    po[9] = fminf(fmaxf(o * 255.0f, 0.0f), 255.0f);
    po[10] = vw * qinv; po[11] = vx * qinv; po[12] = vy * qinv; po[13] = vz * qinv;
}

extern "C" void kernel_launch(void* const* d_in, const int* in_sizes, int n_in,
                              void* d_out, int out_size, void* d_ws, size_t ws_size,
                              hipStream_t stream)
{
    const float* verts   = (const float*)d_in[0];
    const float* xyz     = (const float*)d_in[1];
    const float* opa     = (const float*)d_in[2];
    const float* scl     = (const float*)d_in[3];
    const float* rot     = (const float*)d_in[4];
    const float* fdc     = (const float*)d_in[5];
    // d_in[6] = features_rest : unused by the reference output — never read.
    const int*   faces   = (const int*)d_in[7];
    const int*   binding = (const int*)d_in[8];

    int n      = in_sizes[8];        // N_GAUSS
    int nfaces = in_sizes[7] / 3;    // N_FACES
    float* out = (float*)d_out;

    size_t need = (size_t)nfaces * 5 * sizeof(float4);

    if (ws_size >= need) {
        float4* face = (float4*)d_ws;
        hipLaunchKernelGGL(face_kernel, dim3((nfaces + 255) / 256), dim3(256), 0, stream,
                           verts, faces, face, nfaces);
        hipLaunchKernelGGL(gauss_lds, dim3((n + 255) / 256), dim3(256), 0, stream,
                           xyz, opa, scl, (const float4*)rot, fdc, binding, face, out, n);
    } else {
        hipLaunchKernelGGL(gauss_fused, dim3((n + 255) / 256), dim3(256), 0, stream,
                           verts, faces, xyz, opa, scl, (const float4*)rot, fdc, binding, out, n);
    }
}

// Round 4
// 44.355 us; speedup vs baseline: 2.3420x; 1.0730x over previous
//
#include <hip/hip_runtime.h>
#include <math.h>

// ---------------------------------------------------------------------------
// MyGaussianModel: bind 2M gaussians to 9976 triangle faces.
// Phase 1: per-face quat + center + scale -> 32 B/face table in d_ws
//          (319 KB, L2-resident).
// Phase 2: per-gaussian: gather 2 float4/face, reconstruct R from quat,
//          transform + activations; output transposed through LDS so all
//          global stores are coalesced nontemporal dwordx4.
// ---------------------------------------------------------------------------

typedef float f32x4 __attribute__((ext_vector_type(4)));

struct F3 { float x, y, z; };
__device__ __forceinline__ F3 mkf3(float x, float y, float z) { F3 r; r.x = x; r.y = y; r.z = z; return r; }
__device__ __forceinline__ F3 f3sub(F3 a, F3 b) { return mkf3(a.x - b.x, a.y - b.y, a.z - b.z); }
__device__ __forceinline__ F3 f3add(F3 a, F3 b) { return mkf3(a.x + b.x, a.y + b.y, a.z + b.z); }
__device__ __forceinline__ F3 f3scl(F3 a, float s) { return mkf3(a.x * s, a.y * s, a.z * s); }
__device__ __forceinline__ float f3dot(F3 a, F3 b) { return a.x * b.x + a.y * b.y + a.z * b.z; }
__device__ __forceinline__ F3 f3cross(F3 a, F3 b) {
    return mkf3(a.y * b.z - a.z * b.y, a.z * b.x - a.x * b.z, a.x * b.y - a.y * b.x);
}

__device__ void face_geom(const float* __restrict__ verts, const int* __restrict__ faces, int f,
                          F3& a0, F3& a1, F3& a2, F3& ctr, float& fs, float4& quat_wxyz)
{
    int i0 = faces[3 * f + 0], i1 = faces[3 * f + 1], i2 = faces[3 * f + 2];
    F3 v0 = mkf3(verts[3 * i0], verts[3 * i0 + 1], verts[3 * i0 + 2]);
    F3 v1 = mkf3(verts[3 * i1], verts[3 * i1 + 1], verts[3 * i1 + 2]);
    F3 v2 = mkf3(verts[3 * i2], verts[3 * i2 + 1], verts[3 * i2 + 2]);

    ctr = f3scl(f3add(f3add(v0, v1), v2), (1.0f / 3.0f));

    F3 e1 = f3sub(v1, v0);
    float d1 = f3dot(e1, e1);
    float s0 = sqrtf(d1);
    a0 = f3scl(e1, 1.0f / sqrtf(fmaxf(d1, 1e-20f)));

    F3 e2 = f3sub(v2, v0);
    F3 c = f3cross(a0, e2);
    float dc = f3dot(c, c);
    a1 = f3scl(c, 1.0f / sqrtf(fmaxf(dc, 1e-20f)));

    F3 c2 = f3cross(a1, a0);
    float dc2 = f3dot(c2, c2);
    F3 n2 = f3scl(c2, 1.0f / sqrtf(fmaxf(dc2, 1e-20f)));
    a2 = mkf3(-n2.x, -n2.y, -n2.z);

    float s1 = fabsf(f3dot(c, a1));
    fs = 0.5f * (s0 + s1);

    float r00 = a0.x, r10 = a0.y, r20 = a0.z;
    float r01 = a1.x, r11 = a1.y, r21 = a1.z;
    float r02 = a2.x, r12 = a2.y, r22 = a2.z;
    float t = r00 + r11 + r22;

    float cand[4][4] = {
        { 1.0f + r00 - r11 - r22, r10 + r01,              r20 + r02,              r21 - r12 },
        { r10 + r01,              1.0f - r00 + r11 - r22, r21 + r12,              r02 - r20 },
        { r20 + r02,              r21 + r12,              1.0f - r00 - r11 + r22, r10 - r01 },
        { r21 - r12,              r02 - r20,              r10 - r01,              1.0f + t  }
    };
    float dec[4] = { r00, r11, r22, t };
    int ch = 0;
    float best = dec[0];
#pragma unroll
    for (int j = 1; j < 4; ++j) {
        if (dec[j] > best) { best = dec[j]; ch = j; }
    }
    float qx = cand[ch][0], qy = cand[ch][1], qz = cand[ch][2], qw = cand[ch][3];
    float inv = 1.0f / sqrtf(qx * qx + qy * qy + qz * qz + qw * qw);
    quat_wxyz = make_float4(qw * inv, qx * inv, qy * inv, qz * inv);
}

// Compact table: fd[2f] = quat (w,x,y,z); fd[2f+1] = (cx,cy,cz,fs)
__global__ __launch_bounds__(256)
void face_kernel2(const float* __restrict__ verts, const int* __restrict__ faces,
                  f32x4* __restrict__ fd, int nf)
{
    int f = blockIdx.x * 256 + threadIdx.x;
    if (f >= nf) return;
    F3 a0, a1, a2, ctr; float fs; float4 quat;
    face_geom(verts, faces, f, a0, a1, a2, ctr, fs, quat);
    f32x4 q; q.x = quat.x; q.y = quat.y; q.z = quat.z; q.w = quat.w;
    f32x4 c; c.x = ctr.x;  c.y = ctr.y;  c.z = ctr.z;  c.w = fs;
    fd[2 * f + 0] = q;
    fd[2 * f + 1] = c;
}

// ---------------------------------------------------------------------------
// Main kernel: 256 gaussians/block. Direct (wave-contiguous) input loads,
// R reconstructed from face quat, output transposed via LDS, nt stores.
// ---------------------------------------------------------------------------
__global__ __launch_bounds__(256)
void gauss_q(const float* __restrict__ xyz, const float* __restrict__ opa,
             const float* __restrict__ scl, const f32x4* __restrict__ rot_raw,
             const float* __restrict__ fdc, const int* __restrict__ binding,
             const f32x4* __restrict__ face, float* __restrict__ out, int n)
{
    __shared__ float s_out[256 * 15];   // stride 15: gcd(15,32)=1 -> conflict-free

    int tid = threadIdx.x;
    int g0  = blockIdx.x * 256;
    int cnt = n - g0; if (cnt > 256) cnt = 256;

    if (tid < cnt) {
        int i = g0 + tid;
        int b = binding[i];                       // coalesced dword
        f32x4 q4 = face[2 * b + 0];               // L2-resident gather
        f32x4 cf = face[2 * b + 1];
        float qw = q4.x, qx = q4.y, qy = q4.z, qz = q4.w;
        float fs = cf.w;

        // R from unit quat (Hamilton, matches reference Shepperd inverse)
        float xx = qx * qx, yy = qy * qy, zz = qz * qz;
        float xy = qx * qy, xz = qx * qz, yz = qy * qz;
        float wx = qw * qx, wy = qw * qy, wz = qw * qz;
        float r00 = 1.0f - 2.0f * (yy + zz), r01 = 2.0f * (xy - wz), r02 = 2.0f * (xz + wy);
        float r10 = 2.0f * (xy + wz), r11 = 1.0f - 2.0f * (xx + zz), r12 = 2.0f * (yz - wx);
        float r20 = 2.0f * (xz - wy), r21 = 2.0f * (yz + wx), r22 = 1.0f - 2.0f * (xx + yy);

        float x = xyz[3 * i + 0], y = xyz[3 * i + 1], z = xyz[3 * i + 2];
        float gx = (r00 * x + r01 * y + r02 * z) * fs + cf.x;
        float gy = (r10 * x + r11 * y + r12 * z) * fs + cf.y;
        float gz = (r20 * x + r21 * y + r22 * z) * fs + cf.z;

        float s0 = expf(scl[3 * i + 0]) * fs;
        float s1 = expf(scl[3 * i + 1]) * fs;
        float s2 = expf(scl[3 * i + 2]) * fs;

        float o = 1.0f / (1.0f + expf(-opa[i]));

        f32x4 r = rot_raw[i];
        float rinv = 1.0f / (sqrtf(r.x * r.x + r.y * r.y + r.z * r.z + r.w * r.w) + 1e-12f);
        float rw = r.x * rinv, rx = r.y * rinv, ry = r.z * rinv, rz = r.w * rinv;

        // quat product (fq is unit; reference's /(norm+1e-12) rounds to /1 in f32)
        float vx = qw * rx + rw * qx + (qy * rz - qz * ry);
        float vy = qw * ry + rw * qy + (qz * rx - qx * rz);
        float vz = qw * rz + rw * qz + (qx * ry - qy * rx);
        float vw = qw * rw - (qx * rx + qy * ry + qz * rz);
        float qinv = 1.0f / sqrtf(vx * vx + vy * vy + vz * vz + vw * vw);

        float d0 = fdc[3 * i + 0], d1 = fdc[3 * i + 1], d2 = fdc[3 * i + 2];
        float c0 = fminf(fmaxf((0.5f + 0.282f * d0) * 255.0f, 0.0f), 255.0f);
        float c1 = fminf(fmaxf((0.5f + 0.282f * d1) * 255.0f, 0.0f), 255.0f);
        float c2 = fminf(fmaxf((0.5f + 0.282f * d2) * 255.0f, 0.0f), 255.0f);
        float c3 = fminf(fmaxf(o * 255.0f, 0.0f), 255.0f);

        float* po = &s_out[tid * 15];
        po[0]  = gx;        po[1]  = gy;        po[2]  = gz;
        po[3]  = s0;        po[4]  = s1;        po[5]  = s2;
        po[6]  = c0;        po[7]  = c1;        po[8]  = c2;        po[9] = c3;
        po[10] = vw * qinv; po[11] = vx * qinv; po[12] = vy * qinv; po[13] = vz * qinv;
    }
    __syncthreads();

    // fully-coalesced nontemporal dwordx4 copy-out
    int nflo = cnt * 14;
    int nfo4 = nflo >> 2;                         // 896 (cnt=256) / 448 (cnt=128)
    f32x4* o4 = (f32x4*)(out + (size_t)g0 * 14);  // g0*56 B is 16B-aligned
    for (int j = tid; j < nfo4; j += 256) {
        int fb = 4 * j;
        f32x4 v;
        v.x = s_out[((fb + 0) / 14) * 15 + (fb + 0) % 14];
        v.y = s_out[((fb + 1) / 14) * 15 + (fb + 1) % 14];
        v.z = s_out[((fb + 2) / 14) * 15 + (fb + 2) % 14];
        v.w = s_out[((fb + 3) / 14) * 15 + (fb + 3) % 14];
        __builtin_nontemporal_store(v, o4 + j);
    }
    for (int f = (nfo4 << 2) + tid; f < nflo; f += 256) {
        __builtin_nontemporal_store(s_out[(f / 14) * 15 + f % 14],
                                    out + (size_t)g0 * 14 + f);
    }
}

// Fallback if ws_size is too small for the face table (not expected).
__global__ __launch_bounds__(256)
void gauss_fused(const float* __restrict__ verts, const int* __restrict__ faces,
                 const float* __restrict__ xyz, const float* __restrict__ opa,
                 const float* __restrict__ scl, const f32x4* __restrict__ rot_raw,
                 const float* __restrict__ fdc, const int* __restrict__ binding,
                 float* __restrict__ out, int n)
{
    int i = blockIdx.x * 256 + threadIdx.x;
    if (i >= n) return;
    int b = binding[i];
    F3 a0, a1, a2, ctr; float fs; float4 quat;
    face_geom(verts, faces, b, a0, a1, a2, ctr, fs, quat);

    float x = xyz[3 * i], y = xyz[3 * i + 1], z = xyz[3 * i + 2];
    float gx = (a0.x * x + a1.x * y + a2.x * z) * fs + ctr.x;
    float gy = (a0.y * x + a1.y * y + a2.y * z) * fs + ctr.y;
    float gz = (a0.z * x + a1.z * y + a2.z * z) * fs + ctr.z;
    float s0 = expf(scl[3 * i + 0]) * fs;
    float s1 = expf(scl[3 * i + 1]) * fs;
    float s2 = expf(scl[3 * i + 2]) * fs;
    float o = 1.0f / (1.0f + expf(-opa[i]));
    f32x4 r = rot_raw[i];
    float rinv = 1.0f / (sqrtf(r.x * r.x + r.y * r.y + r.z * r.z + r.w * r.w) + 1e-12f);
    float rw = r.x * rinv, rx = r.y * rinv, ry = r.z * rinv, rz = r.w * rinv;
    float pw = quat.x, px = quat.y, py = quat.z, pz = quat.w;
    float vx = pw * rx + rw * px + (py * rz - pz * ry);
    float vy = pw * ry + rw * py + (pz * rx - px * rz);
    float vz = pw * rz + rw * pz + (px * ry - py * rx);
    float vw = pw * rw - (px * rx + py * ry + pz * rz);
    float qinv = 1.0f / sqrtf(vx * vx + vy * vy + vz * vz + vw * vw);
    float* po = out + (size_t)i * 14;
    po[0] = gx; po[1] = gy; po[2] = gz;
    po[3] = s0; po[4] = s1; po[5] = s2;
    po[6] = fminf(fmaxf((0.5f + 0.282f * fdc[3 * i + 0]) * 255.0f, 0.0f), 255.0f);
    po[7] = fminf(fmaxf((0.5f + 0.282f * fdc[3 * i + 1]) * 255.0f, 0.0f), 255.0f);
    po[8] = fminf(fmaxf((0.5f + 0.282f * fdc[3 * i + 2]) * 255.0f, 0.0f), 255.0f);
    po[9] = fminf(fmaxf(o * 255.0f, 0.0f), 255.0f);
    po[10] = vw * qinv; po[11] = vx * qinv; po[12] = vy * qinv; po[13] = vz * qinv;
}

extern "C" void kernel_launch(void* const* d_in, const int* in_sizes, int n_in,
                              void* d_out, int out_size, void* d_ws, size_t ws_size,
                              hipStream_t stream)
{
    const float* verts   = (const float*)d_in[0];
    const float* xyz     = (const float*)d_in[1];
    const float* opa     = (const float*)d_in[2];
    const float* scl     = (const float*)d_in[3];
    const float* rot     = (const float*)d_in[4];
    const float* fdc     = (const float*)d_in[5];
    // d_in[6] = features_rest : unused by the reference output — never read.
    const int*   faces   = (const int*)d_in[7];
    const int*   binding = (const int*)d_in[8];

    int n      = in_sizes[8];        // N_GAUSS
    int nfaces = in_sizes[7] / 3;    // N_FACES
    float* out = (float*)d_out;

    size_t need = (size_t)nfaces * 2 * sizeof(f32x4);

    if (ws_size >= need) {
        f32x4* face = (f32x4*)d_ws;
        hipLaunchKernelGGL(face_kernel2, dim3((nfaces + 255) / 256), dim3(256), 0, stream,
                           verts, faces, face, nfaces);
        hipLaunchKernelGGL(gauss_q, dim3((n + 255) / 256), dim3(256), 0, stream,
                           xyz, opa, scl, (const f32x4*)rot, fdc, binding, face, out, n);
    } else {
        hipLaunchKernelGGL(gauss_fused, dim3((n + 255) / 256), dim3(256), 0, stream,
                           verts, faces, xyz, opa, scl, (const f32x4*)rot, fdc, binding, out, n);
    }
}